// Round 1
// baseline (470.313 us; speedup 1.0000x reference)
//
#include <hip/hip_runtime.h>
#include <math.h>

#define NNODES 50000
#define NEDGES 400000
#define INC    128
#define HC1    256   // HEADS*HID
#define NHEADS 8
#define OUTC   64
#define NK     16
#define NEG_SLOPE 0.2f
#define EPS_F  1e-16f

__device__ __forceinline__ float lrelu(float x){ return x > 0.f ? x : NEG_SLOPE * x; }
__device__ __forceinline__ float eluf(float x){ return x > 0.f ? x : (expf(x) - 1.f); }

// ---------------- CSR build ----------------
__global__ void count_deg_k(const int* __restrict__ dst, int* __restrict__ deg){
    int e = blockIdx.x * 256 + threadIdx.x;
    if (e < NEDGES) atomicAdd(&deg[dst[e]], 1);
}

__global__ void blocksum_k(const int* __restrict__ deg, int* __restrict__ bsum){
    __shared__ int sm[4];
    int i = blockIdx.x * 256 + threadIdx.x;
    int v = (i < NNODES) ? deg[i] : 0;
    for (int off = 1; off < 64; off <<= 1) v += __shfl_xor(v, off);
    int lane = threadIdx.x & 63, wid = threadIdx.x >> 6;
    if (lane == 0) sm[wid] = v;
    __syncthreads();
    if (threadIdx.x == 0) bsum[blockIdx.x] = sm[0] + sm[1] + sm[2] + sm[3];
}

__global__ void scan_bsum_k(const int* __restrict__ bsum, int* __restrict__ boff, int nb){
    int tid = threadIdx.x;
    int v = (tid < nb) ? bsum[tid] : 0;
    int orig = v;
    int lane = tid & 63, wid = tid >> 6;
    for (int off = 1; off < 64; off <<= 1){ int t = __shfl_up(v, off); if (lane >= off) v += t; }
    __shared__ int wsum[4];
    if (lane == 63) wsum[wid] = v;
    __syncthreads();
    int add = 0;
    for (int w = 0; w < wid; w++) add += wsum[w];
    v += add;
    if (tid < nb) boff[tid] = v - orig;   // exclusive prefix of block sums
}

__global__ void scan_write_k(const int* __restrict__ deg, const int* __restrict__ boff,
                             int* __restrict__ rowptr){
    int tid = threadIdx.x;
    int i = blockIdx.x * 256 + tid;
    int v = (i < NNODES) ? deg[i] : 0;
    int lane = tid & 63, wid = tid >> 6;
    int sv = v;
    for (int off = 1; off < 64; off <<= 1){ int t = __shfl_up(sv, off); if (lane >= off) sv += t; }
    __shared__ int wsum[4];
    if (lane == 63) wsum[wid] = sv;
    __syncthreads();
    int add = 0;
    for (int w = 0; w < wid; w++) add += wsum[w];
    sv += add;
    if (i < NNODES) rowptr[i + 1] = boff[blockIdx.x] + sv;
    if (i == 0) rowptr[0] = 0;
}

__global__ void fill_csr_k(const int* __restrict__ src, const int* __restrict__ dst,
                           const int* __restrict__ rowptr, int* __restrict__ fillc,
                           int* __restrict__ col){
    int e = blockIdx.x * 256 + threadIdx.x;
    if (e < NEDGES){
        int d = dst[e];
        int pos = atomicAdd(&fillc[d], 1);
        col[rowptr[d] + pos] = src[e];
    }
}

// ---------------- fp32 tiled GEMM: C[M,Nc] = A[M,KTOT] @ B[KTOT,Nc] ----------------
template<int KTOT>
__global__ void gemm_k(const float* __restrict__ A, const float* __restrict__ B,
                       float* __restrict__ C, int M, int Nc){
    __shared__ float As[16][68];   // k-major, padded (68*4B = 272B stride, 16B aligned)
    __shared__ float Bs[16][68];
    int tx = threadIdx.x;          // 256 threads
    int tm = tx >> 4, tn = tx & 15;
    int m0 = blockIdx.x * 64, n0 = blockIdx.y * 64;
    float acc[4][4];
#pragma unroll
    for (int i = 0; i < 4; i++)
#pragma unroll
        for (int j = 0; j < 4; j++) acc[i][j] = 0.f;

    int r  = tx >> 2;          // 0..63 (A row within tile)
    int kq = (tx & 3) * 4;     // k quad
    int kk = tx >> 4;          // 0..15 (B k row)
    int nn = (tx & 15) * 4;    // B col quad

    for (int kt = 0; kt < KTOT; kt += 16){
        float4 av = make_float4(0.f, 0.f, 0.f, 0.f);
        int row = m0 + r;
        if (row < M) av = *(const float4*)(A + (size_t)row * KTOT + kt + kq);
        As[kq + 0][r] = av.x; As[kq + 1][r] = av.y; As[kq + 2][r] = av.z; As[kq + 3][r] = av.w;
        float4 bv = *(const float4*)(B + (size_t)(kt + kk) * Nc + n0 + nn);
        *(float4*)&Bs[kk][nn] = bv;
        __syncthreads();
#pragma unroll
        for (int k = 0; k < 16; k++){
            float4 a4 = *(float4*)&As[k][tm * 4];
            float4 b4 = *(float4*)&Bs[k][tn * 4];
            float a[4] = {a4.x, a4.y, a4.z, a4.w};
            float b[4] = {b4.x, b4.y, b4.z, b4.w};
#pragma unroll
            for (int i = 0; i < 4; i++)
#pragma unroll
                for (int j = 0; j < 4; j++) acc[i][j] += a[i] * b[j];
        }
        __syncthreads();
    }
#pragma unroll
    for (int i = 0; i < 4; i++){
        int row = m0 + tm * 4 + i;
        if (row < M){
            float4 o = make_float4(acc[i][0], acc[i][1], acc[i][2], acc[i][3]);
            *(float4*)(C + (size_t)row * Nc + n0 + tn * 4) = o;
        }
    }
}

// ---------------- attention scores ----------------
// layer 1: a_src[n,h] = sum_c h1[n, h*32+c] * att_s[h*32+c]; lane covers 4 channels.
__global__ void att1_k(const float* __restrict__ h1, const float* __restrict__ att_s,
                       const float* __restrict__ att_d,
                       float* __restrict__ as1, float* __restrict__ ad1){
    int lane = threadIdx.x & 63, wid = threadIdx.x >> 6;
    int n = blockIdx.x * 4 + wid;
    float4 hv = *(const float4*)(h1 + (size_t)n * HC1 + lane * 4);
    float4 sv = *(const float4*)(att_s + lane * 4);
    float4 dv = *(const float4*)(att_d + lane * 4);
    float ps = hv.x * sv.x + hv.y * sv.y + hv.z * sv.z + hv.w * sv.w;
    float pd = hv.x * dv.x + hv.y * dv.y + hv.z * dv.z + hv.w * dv.w;
    for (int m = 1; m < 8; m <<= 1){ ps += __shfl_xor(ps, m); pd += __shfl_xor(pd, m); }
    if ((lane & 7) == 0){
        int h = lane >> 3;
        as1[n * NHEADS + h] = ps;
        ad1[n * NHEADS + h] = pd;
    }
}

__global__ void att2_k(const float* __restrict__ h2, const float* __restrict__ att_s,
                       const float* __restrict__ att_d,
                       float* __restrict__ as2, float* __restrict__ ad2){
    int lane = threadIdx.x & 63, wid = threadIdx.x >> 6;
    int n = blockIdx.x * 4 + wid;
    float hv = h2[(size_t)n * OUTC + lane];
    float ps = hv * att_s[lane];
    float pd = hv * att_d[lane];
    for (int m = 1; m < 64; m <<= 1){ ps += __shfl_xor(ps, m); pd += __shfl_xor(pd, m); }
    if (lane == 0){ as2[n] = ps; ad2[n] = pd; }
}

// ---------------- GAT layer 1 aggregation: one wave per destination node ----------------
__global__ void gat1_agg_k(const float* __restrict__ h1, const float* __restrict__ as1,
                           const float* __restrict__ ad1, const int* __restrict__ rowptr,
                           const int* __restrict__ col, const float* __restrict__ b1,
                           float* __restrict__ outp){
    int lane = threadIdx.x & 63, wid = threadIdx.x >> 6;
    int d = blockIdx.x * 4 + wid;
    int row0 = rowptr[d];
    int deg  = rowptr[d + 1] - row0;

    // phase 1/2 layout: lane = j*8 + h  (j = edge slot, h = head)
    int h8 = lane & 7, j = lane >> 3;
    float adst      = ad1[d * NHEADS + h8];
    float asrc_self = as1[d * NHEADS + h8];
    float e_self = lrelu(asrc_self + adst);

    float vmax = e_self;
    for (int base = 0; base < deg; base += 8){
        int idx = base + j;
        if (idx < deg){
            int s = col[row0 + idx];
            vmax = fmaxf(vmax, lrelu(as1[s * NHEADS + h8] + adst));
        }
    }
    vmax = fmaxf(vmax, __shfl_xor(vmax, 8));
    vmax = fmaxf(vmax, __shfl_xor(vmax, 16));
    vmax = fmaxf(vmax, __shfl_xor(vmax, 32));

    float vsum = (j == 0) ? expf(e_self - vmax) : 0.f;
    for (int base = 0; base < deg; base += 8){
        int idx = base + j;
        if (idx < deg){
            int s = col[row0 + idx];
            vsum += expf(lrelu(as1[s * NHEADS + h8] + adst) - vmax);
        }
    }
    vsum += __shfl_xor(vsum, 8);
    vsum += __shfl_xor(vsum, 16);
    vsum += __shfl_xor(vsum, 32);
    float den = vsum + EPS_F;

    // phase 3 layout: lane covers channels 4*lane..4*lane+3, head = lane>>3
    int hc = lane >> 3;
    float m_c    = __shfl(vmax, hc);     // lane hc holds head hc (j=0)
    float den_c  = __shfl(den, hc);
    float adst_c = __shfl(adst, hc);
    float asrc_d = __shfl(asrc_self, hc);
    int cbase = lane * 4;

    float alpha = expf(lrelu(asrc_d + adst_c) - m_c) / den_c;  // self-loop
    float4 hv = *(const float4*)(h1 + (size_t)d * HC1 + cbase);
    float4 acc = make_float4(alpha * hv.x, alpha * hv.y, alpha * hv.z, alpha * hv.w);

    for (int idx = 0; idx < deg; idx++){
        int s = col[row0 + idx];
        float a = expf(lrelu(as1[s * NHEADS + hc] + adst_c) - m_c) / den_c;
        float4 h4 = *(const float4*)(h1 + (size_t)s * HC1 + cbase);
        acc.x += a * h4.x; acc.y += a * h4.y; acc.z += a * h4.z; acc.w += a * h4.w;
    }
    float4 bb = *(const float4*)(b1 + cbase);
    acc.x = eluf(acc.x + bb.x); acc.y = eluf(acc.y + bb.y);
    acc.z = eluf(acc.z + bb.z); acc.w = eluf(acc.w + bb.w);
    *(float4*)(outp + (size_t)d * HC1 + cbase) = acc;
}

// ---------------- GAT layer 2 aggregation (1 head, 64 ch) ----------------
__global__ void gat2_agg_k(const float* __restrict__ h2, const float* __restrict__ as2,
                           const float* __restrict__ ad2, const int* __restrict__ rowptr,
                           const int* __restrict__ col, const float* __restrict__ b2,
                           float* __restrict__ emb){
    int lane = threadIdx.x & 63, wid = threadIdx.x >> 6;
    int d = blockIdx.x * 4 + wid;
    int row0 = rowptr[d];
    int deg  = rowptr[d + 1] - row0;

    float adst = ad2[d];
    float e_self = lrelu(as2[d] + adst);
    float vmax = e_self;
    for (int base = 0; base < deg; base += 64){
        int idx = base + lane;
        if (idx < deg){
            int s = col[row0 + idx];
            vmax = fmaxf(vmax, lrelu(as2[s] + adst));
        }
    }
    for (int m = 1; m < 64; m <<= 1) vmax = fmaxf(vmax, __shfl_xor(vmax, m));

    float vsum = (lane == 0) ? expf(e_self - vmax) : 0.f;
    for (int base = 0; base < deg; base += 64){
        int idx = base + lane;
        if (idx < deg){
            int s = col[row0 + idx];
            vsum += expf(lrelu(as2[s] + adst) - vmax);
        }
    }
    for (int m = 1; m < 64; m <<= 1) vsum += __shfl_xor(vsum, m);
    float den = vsum + EPS_F;

    float alpha = expf(e_self - vmax) / den;
    float acc = alpha * h2[(size_t)d * OUTC + lane];
    for (int idx = 0; idx < deg; idx++){
        int s = col[row0 + idx];
        float a = expf(lrelu(as2[s] + adst) - vmax) / den;
        acc += a * h2[(size_t)s * OUTC + lane];
    }
    emb[(size_t)d * OUTC + lane] = acc + b2[lane];
}

// ---------------- MLP head + softmax: one wave per node ----------------
__global__ void mlp_k(const float* __restrict__ emb, const float* __restrict__ Wm1,
                      const float* __restrict__ bm1, const float* __restrict__ Wm2,
                      const float* __restrict__ bm2, float* __restrict__ sout){
    __shared__ float semb[4][64];
    __shared__ float shid[4][128];
    int lane = threadIdx.x & 63, wid = threadIdx.x >> 6;
    int d = blockIdx.x * 4 + wid;

    semb[wid][lane] = emb[(size_t)d * OUTC + lane];
    __syncthreads();

    float h0 = bm1[lane], h1v = bm1[64 + lane];
    for (int c = 0; c < 64; c++){
        float e = semb[wid][c];
        h0  += e * Wm1[c * 128 + lane];
        h1v += e * Wm1[c * 128 + 64 + lane];
    }
    shid[wid][lane]      = fmaxf(h0, 0.f);
    shid[wid][64 + lane] = fmaxf(h1v, 0.f);
    __syncthreads();

    if (lane < NK){
        float lg = bm2[lane];
        for (int jj = 0; jj < 128; jj++) lg += shid[wid][jj] * Wm2[jj * NK + lane];
        float m = lg;
        for (int msk = 1; msk < NK; msk <<= 1) m = fmaxf(m, __shfl_xor(m, msk, NK));
        float ex = expf(lg - m);
        float s = ex;
        for (int msk = 1; msk < NK; msk <<= 1) s += __shfl_xor(s, msk, NK);
        sout[(size_t)d * NK + lane] = ex / s;
    }
}

// ---------------- launcher ----------------
extern "C" void kernel_launch(void* const* d_in, const int* in_sizes, int n_in,
                              void* d_out, int out_size, void* d_ws, size_t ws_size,
                              hipStream_t stream){
    const float* x      = (const float*)d_in[0];
    const int*   ei     = (const int*)d_in[1];
    const int*   srcv   = ei;
    const int*   dstv   = ei + NEDGES;
    const float* W1     = (const float*)d_in[2];
    const float* att_s1 = (const float*)d_in[3];
    const float* att_d1 = (const float*)d_in[4];
    const float* b1     = (const float*)d_in[5];
    const float* W2     = (const float*)d_in[6];
    const float* att_s2 = (const float*)d_in[7];
    const float* att_d2 = (const float*)d_in[8];
    const float* b2     = (const float*)d_in[9];
    const float* Wm1    = (const float*)d_in[10];
    const float* bm1    = (const float*)d_in[11];
    const float* Wm2    = (const float*)d_in[12];
    const float* bm2    = (const float*)d_in[13];

    float* out     = (float*)d_out;                     // s: [N,16]
    float* emb_out = out + (size_t)NNODES * NK;         // embeddings: [N,64]

    // workspace layout (h2 aliases h1: h1 dead after gat1_agg, h2 born at gemm2)
    float* ws  = (float*)d_ws;
    float* h1  = ws;                                    // N*256
    float* h2  = h1;                                    // N*64 (alias, lifetime disjoint)
    float* hL1 = h1 + (size_t)NNODES * HC1;             // N*256
    float* as1 = hL1 + (size_t)NNODES * HC1;            // N*8
    float* ad1 = as1 + (size_t)NNODES * NHEADS;         // N*8
    float* as2 = ad1 + (size_t)NNODES * NHEADS;         // N
    float* ad2 = as2 + NNODES;                          // N
    int* deg    = (int*)(ad2 + NNODES);                 // N
    int* rowptr = deg + NNODES;                         // N+1
    int* bsum   = rowptr + NNODES + 1;                  // 256
    int* boff   = bsum + 256;                           // 256
    int* fillc  = boff + 256;                           // N
    int* colv   = fillc + NNODES;                       // E

    hipMemsetAsync(deg, 0, NNODES * sizeof(int), stream);
    hipMemsetAsync(fillc, 0, NNODES * sizeof(int), stream);

    const int NB = (NNODES + 255) / 256;   // 196
    count_deg_k<<<(NEDGES + 255) / 256, 256, 0, stream>>>(dstv, deg);
    blocksum_k<<<NB, 256, 0, stream>>>(deg, bsum);
    scan_bsum_k<<<1, 256, 0, stream>>>(bsum, boff, NB);
    scan_write_k<<<NB, 256, 0, stream>>>(deg, boff, rowptr);
    fill_csr_k<<<(NEDGES + 255) / 256, 256, 0, stream>>>(srcv, dstv, rowptr, fillc, colv);

    // layer 1
    gemm_k<INC><<<dim3((NNODES + 63) / 64, HC1 / 64), 256, 0, stream>>>(x, W1, h1, NNODES, HC1);
    att1_k<<<NNODES / 4, 256, 0, stream>>>(h1, att_s1, att_d1, as1, ad1);
    gat1_agg_k<<<NNODES / 4, 256, 0, stream>>>(h1, as1, ad1, rowptr, colv, b1, hL1);

    // layer 2
    gemm_k<HC1><<<dim3((NNODES + 63) / 64, OUTC / 64), 256, 0, stream>>>(hL1, W2, h2, NNODES, OUTC);
    att2_k<<<NNODES / 4, 256, 0, stream>>>(h2, att_s2, att_d2, as2, ad2);
    gat2_agg_k<<<NNODES / 4, 256, 0, stream>>>(h2, as2, ad2, rowptr, colv, b2, emb_out);

    // MLP head + softmax
    mlp_k<<<NNODES / 4, 256, 0, stream>>>(emb_out, Wm1, bm1, Wm2, bm2, out);
}

// Round 2
// 414.278 us; speedup vs baseline: 1.1353x; 1.1353x over previous
//
#include <hip/hip_runtime.h>
#include <math.h>

#define NNODES 50000
#define NEDGES 400000
#define INC    128
#define HC1    256   // HEADS*HID
#define NHEADS 8
#define OUTC   64
#define NK     16
#define NEG_SLOPE 0.2f
#define EPS_F  1e-16f

__device__ __forceinline__ float lrelu(float x){ return x > 0.f ? x : NEG_SLOPE * x; }
__device__ __forceinline__ float eluf(float x){ return x > 0.f ? x : (expf(x) - 1.f); }

// ---------------- CSR build ----------------
__global__ void count_deg_k(const int* __restrict__ dst, int* __restrict__ deg){
    int e = blockIdx.x * 256 + threadIdx.x;
    if (e < NEDGES) atomicAdd(&deg[dst[e]], 1);
}

__global__ void blocksum_k(const int* __restrict__ deg, int* __restrict__ bsum){
    __shared__ int sm[4];
    int i = blockIdx.x * 256 + threadIdx.x;
    int v = (i < NNODES) ? deg[i] : 0;
    for (int off = 1; off < 64; off <<= 1) v += __shfl_xor(v, off);
    int lane = threadIdx.x & 63, wid = threadIdx.x >> 6;
    if (lane == 0) sm[wid] = v;
    __syncthreads();
    if (threadIdx.x == 0) bsum[blockIdx.x] = sm[0] + sm[1] + sm[2] + sm[3];
}

__global__ void scan_bsum_k(const int* __restrict__ bsum, int* __restrict__ boff, int nb){
    int tid = threadIdx.x;
    int v = (tid < nb) ? bsum[tid] : 0;
    int orig = v;
    int lane = tid & 63, wid = tid >> 6;
    for (int off = 1; off < 64; off <<= 1){ int t = __shfl_up(v, off); if (lane >= off) v += t; }
    __shared__ int wsum[4];
    if (lane == 63) wsum[wid] = v;
    __syncthreads();
    int add = 0;
    for (int w = 0; w < wid; w++) add += wsum[w];
    v += add;
    if (tid < nb) boff[tid] = v - orig;   // exclusive prefix of block sums
}

__global__ void scan_write_k(const int* __restrict__ deg, const int* __restrict__ boff,
                             int* __restrict__ rowptr){
    int tid = threadIdx.x;
    int i = blockIdx.x * 256 + tid;
    int v = (i < NNODES) ? deg[i] : 0;
    int lane = tid & 63, wid = tid >> 6;
    int sv = v;
    for (int off = 1; off < 64; off <<= 1){ int t = __shfl_up(sv, off); if (lane >= off) sv += t; }
    __shared__ int wsum[4];
    if (lane == 63) wsum[wid] = sv;
    __syncthreads();
    int add = 0;
    for (int w = 0; w < wid; w++) add += wsum[w];
    sv += add;
    if (i < NNODES) rowptr[i + 1] = boff[blockIdx.x] + sv;
    if (i == 0) rowptr[0] = 0;
}

__global__ void fill_csr_k(const int* __restrict__ src, const int* __restrict__ dst,
                           const int* __restrict__ rowptr, int* __restrict__ fillc,
                           int* __restrict__ col){
    int e = blockIdx.x * 256 + threadIdx.x;
    if (e < NEDGES){
        int d = dst[e];
        int pos = atomicAdd(&fillc[d], 1);
        col[rowptr[d] + pos] = src[e];
    }
}

// ---------------- fp32 tiled GEMM: C[M,Nc] = A[M,KTOT] @ B[KTOT,Nc] ----------------
template<int KTOT>
__global__ void gemm_k(const float* __restrict__ A, const float* __restrict__ B,
                       float* __restrict__ C, int M, int Nc){
    __shared__ float As[16][68];   // k-major, padded
    __shared__ float Bs[16][68];
    int tx = threadIdx.x;          // 256 threads
    int tm = tx >> 4, tn = tx & 15;
    int m0 = blockIdx.x * 64, n0 = blockIdx.y * 64;
    float acc[4][4];
#pragma unroll
    for (int i = 0; i < 4; i++)
#pragma unroll
        for (int j = 0; j < 4; j++) acc[i][j] = 0.f;

    int r  = tx >> 2;          // 0..63 (A row within tile)
    int kq = (tx & 3) * 4;     // k quad
    int kk = tx >> 4;          // 0..15 (B k row)
    int nn = (tx & 15) * 4;    // B col quad

    for (int kt = 0; kt < KTOT; kt += 16){
        float4 av = make_float4(0.f, 0.f, 0.f, 0.f);
        int row = m0 + r;
        if (row < M) av = *(const float4*)(A + (size_t)row * KTOT + kt + kq);
        As[kq + 0][r] = av.x; As[kq + 1][r] = av.y; As[kq + 2][r] = av.z; As[kq + 3][r] = av.w;
        float4 bv = *(const float4*)(B + (size_t)(kt + kk) * Nc + n0 + nn);
        *(float4*)&Bs[kk][nn] = bv;
        __syncthreads();
#pragma unroll
        for (int k = 0; k < 16; k++){
            float4 a4 = *(float4*)&As[k][tm * 4];
            float4 b4 = *(float4*)&Bs[k][tn * 4];
            float a[4] = {a4.x, a4.y, a4.z, a4.w};
            float b[4] = {b4.x, b4.y, b4.z, b4.w};
#pragma unroll
            for (int i = 0; i < 4; i++)
#pragma unroll
                for (int j = 0; j < 4; j++) acc[i][j] += a[i] * b[j];
        }
        __syncthreads();
    }
#pragma unroll
    for (int i = 0; i < 4; i++){
        int row = m0 + tm * 4 + i;
        if (row < M){
            float4 o = make_float4(acc[i][0], acc[i][1], acc[i][2], acc[i][3]);
            *(float4*)(C + (size_t)row * Nc + n0 + tn * 4) = o;
        }
    }
}

// ---------------- attention scores ----------------
__global__ void att1_k(const float* __restrict__ h1, const float* __restrict__ att_s,
                       const float* __restrict__ att_d,
                       float* __restrict__ as1, float* __restrict__ ad1){
    int lane = threadIdx.x & 63, wid = threadIdx.x >> 6;
    int n = blockIdx.x * 4 + wid;
    float4 hv = *(const float4*)(h1 + (size_t)n * HC1 + lane * 4);
    float4 sv = *(const float4*)(att_s + lane * 4);
    float4 dv = *(const float4*)(att_d + lane * 4);
    float ps = hv.x * sv.x + hv.y * sv.y + hv.z * sv.z + hv.w * sv.w;
    float pd = hv.x * dv.x + hv.y * dv.y + hv.z * dv.z + hv.w * dv.w;
    for (int m = 1; m < 8; m <<= 1){ ps += __shfl_xor(ps, m); pd += __shfl_xor(pd, m); }
    if ((lane & 7) == 0){
        int h = lane >> 3;
        as1[n * NHEADS + h] = ps;
        ad1[n * NHEADS + h] = pd;
    }
}

__global__ void att2_k(const float* __restrict__ h2, const float* __restrict__ att_s,
                       const float* __restrict__ att_d,
                       float* __restrict__ as2, float* __restrict__ ad2){
    int lane = threadIdx.x & 63, wid = threadIdx.x >> 6;
    int n = blockIdx.x * 4 + wid;
    float hv = h2[(size_t)n * OUTC + lane];
    float ps = hv * att_s[lane];
    float pd = hv * att_d[lane];
    for (int m = 1; m < 64; m <<= 1){ ps += __shfl_xor(ps, m); pd += __shfl_xor(pd, m); }
    if (lane == 0){ as2[n] = ps; ad2[n] = pd; }
}

// ---------------- GAT layer 1 aggregation: one wave per destination node ----------------
__global__ void gat1_agg_k(const float* __restrict__ h1, const float* __restrict__ as1,
                           const float* __restrict__ ad1, const int* __restrict__ rowptr,
                           const int* __restrict__ col, const float* __restrict__ b1,
                           float* __restrict__ outp){
    int lane = threadIdx.x & 63, wid = threadIdx.x >> 6;
    int d = blockIdx.x * 4 + wid;
    int row0 = rowptr[d];
    int deg  = rowptr[d + 1] - row0;

    int h8 = lane & 7, j = lane >> 3;
    float adst      = ad1[d * NHEADS + h8];
    float asrc_self = as1[d * NHEADS + h8];
    float e_self = lrelu(asrc_self + adst);

    float vmax = e_self;
    for (int base = 0; base < deg; base += 8){
        int idx = base + j;
        if (idx < deg){
            int s = col[row0 + idx];
            vmax = fmaxf(vmax, lrelu(as1[s * NHEADS + h8] + adst));
        }
    }
    vmax = fmaxf(vmax, __shfl_xor(vmax, 8));
    vmax = fmaxf(vmax, __shfl_xor(vmax, 16));
    vmax = fmaxf(vmax, __shfl_xor(vmax, 32));

    float vsum = (j == 0) ? expf(e_self - vmax) : 0.f;
    for (int base = 0; base < deg; base += 8){
        int idx = base + j;
        if (idx < deg){
            int s = col[row0 + idx];
            vsum += expf(lrelu(as1[s * NHEADS + h8] + adst) - vmax);
        }
    }
    vsum += __shfl_xor(vsum, 8);
    vsum += __shfl_xor(vsum, 16);
    vsum += __shfl_xor(vsum, 32);
    float den = vsum + EPS_F;

    int hc = lane >> 3;
    float m_c    = __shfl(vmax, hc);
    float den_c  = __shfl(den, hc);
    float adst_c = __shfl(adst, hc);
    float asrc_d = __shfl(asrc_self, hc);
    int cbase = lane * 4;

    float alpha = expf(lrelu(asrc_d + adst_c) - m_c) / den_c;  // self-loop
    float4 hv = *(const float4*)(h1 + (size_t)d * HC1 + cbase);
    float4 acc = make_float4(alpha * hv.x, alpha * hv.y, alpha * hv.z, alpha * hv.w);

    for (int idx = 0; idx < deg; idx++){
        int s = col[row0 + idx];
        float a = expf(lrelu(as1[s * NHEADS + hc] + adst_c) - m_c) / den_c;
        float4 h4 = *(const float4*)(h1 + (size_t)s * HC1 + cbase);
        acc.x += a * h4.x; acc.y += a * h4.y; acc.z += a * h4.z; acc.w += a * h4.w;
    }
    float4 bb = *(const float4*)(b1 + cbase);
    acc.x = eluf(acc.x + bb.x); acc.y = eluf(acc.y + bb.y);
    acc.z = eluf(acc.z + bb.z); acc.w = eluf(acc.w + bb.w);
    *(float4*)(outp + (size_t)d * HC1 + cbase) = acc;
}

// ---------------- GAT layer 2 aggregation (1 head, 64 ch) ----------------
__global__ void gat2_agg_k(const float* __restrict__ h2, const float* __restrict__ as2,
                           const float* __restrict__ ad2, const int* __restrict__ rowptr,
                           const int* __restrict__ col, const float* __restrict__ b2,
                           float* __restrict__ emb){
    int lane = threadIdx.x & 63, wid = threadIdx.x >> 6;
    int d = blockIdx.x * 4 + wid;
    int row0 = rowptr[d];
    int deg  = rowptr[d + 1] - row0;

    float adst = ad2[d];
    float e_self = lrelu(as2[d] + adst);
    float vmax = e_self;
    for (int base = 0; base < deg; base += 64){
        int idx = base + lane;
        if (idx < deg){
            int s = col[row0 + idx];
            vmax = fmaxf(vmax, lrelu(as2[s] + adst));
        }
    }
    for (int m = 1; m < 64; m <<= 1) vmax = fmaxf(vmax, __shfl_xor(vmax, m));

    float vsum = (lane == 0) ? expf(e_self - vmax) : 0.f;
    for (int base = 0; base < deg; base += 64){
        int idx = base + lane;
        if (idx < deg){
            int s = col[row0 + idx];
            vsum += expf(lrelu(as2[s] + adst) - vmax);
        }
    }
    for (int m = 1; m < 64; m <<= 1) vsum += __shfl_xor(vsum, m);
    float den = vsum + EPS_F;

    float alpha = expf(e_self - vmax) / den;
    float acc = alpha * h2[(size_t)d * OUTC + lane];
    for (int idx = 0; idx < deg; idx++){
        int s = col[row0 + idx];
        float a = expf(lrelu(as2[s] + adst) - vmax) / den;
        acc += a * h2[(size_t)s * OUTC + lane];
    }
    emb[(size_t)d * OUTC + lane] = acc + b2[lane];
}

// ---------------- MLP head + softmax: LDS-resident weights, 4 nodes/wave ----------------
// LDS budget: W1a+W1b 32KB + W2t 8.25KB + semb 4KB + shid 8.25KB + biases ~53KB -> 2-3 blocks/CU
__global__ __launch_bounds__(256, 2) void mlp_k(const float* __restrict__ emb,
                      const float* __restrict__ Wm1, const float* __restrict__ bm1,
                      const float* __restrict__ Wm2, const float* __restrict__ bm2,
                      float* __restrict__ sout){
    __shared__ float W1a[64][64];     // [c][j]    (j = 0..63)
    __shared__ float W1b[64][64];     // [c][j-64] (j = 64..127)
    __shared__ float W2t[16][132];    // transposed, padded: [k][j]
    __shared__ float b1s[128];
    __shared__ float b2s[16];
    __shared__ float semb[4][64][4];  // [wave][c][node]
    __shared__ float shid[4][4][132]; // [wave][node][j], padded

    int tx = threadIdx.x;
    for (int i = tx; i < 64 * 64; i += 256){
        int c = i >> 6, l = i & 63;
        W1a[c][l] = Wm1[c * 128 + l];
        W1b[c][l] = Wm1[c * 128 + 64 + l];
    }
    for (int i = tx; i < 16 * 128; i += 256){
        int k = i >> 7, j = i & 127;
        W2t[k][j] = Wm2[j * NK + k];
    }
    if (tx < 128) b1s[tx] = bm1[tx];
    if (tx < 16)  b2s[tx] = bm2[tx];
    __syncthreads();

    int lane = tx & 63, wid = tx >> 6;
    int k16 = lane & 15, ni = lane >> 4;

    // 50000 = 16 * 3125: every block-iteration handles exactly 16 valid nodes.
    for (int base = blockIdx.x * 16; base < NNODES; base += gridDim.x * 16){
        int d0 = base + wid * 4;
        // stage 4 emb rows, transposed to [c][node]
#pragma unroll
        for (int i = 0; i < 4; i++)
            semb[wid][lane][i] = emb[(size_t)(d0 + i) * OUTC + lane];
        __syncthreads();

        float2 acc[4];  // acc[i] = (h[lane], h[64+lane]) for node i
#pragma unroll
        for (int i = 0; i < 4; i++) acc[i] = make_float2(b1s[lane], b1s[64 + lane]);
#pragma unroll 8
        for (int c = 0; c < 64; c++){
            float wa = W1a[c][lane];
            float wb = W1b[c][lane];
            float4 e = *(const float4*)&semb[wid][c][0];
            acc[0].x += e.x * wa; acc[0].y += e.x * wb;
            acc[1].x += e.y * wa; acc[1].y += e.y * wb;
            acc[2].x += e.z * wa; acc[2].y += e.z * wb;
            acc[3].x += e.w * wa; acc[3].y += e.w * wb;
        }
#pragma unroll
        for (int i = 0; i < 4; i++){
            shid[wid][i][lane]      = fmaxf(acc[i].x, 0.f);
            shid[wid][i][64 + lane] = fmaxf(acc[i].y, 0.f);
        }
        __syncthreads();

        // logits: lane = (node ni, class k16); all 64 lanes active
        float lg = b2s[k16];
        const float* hp = &shid[wid][ni][0];
        const float* wp = &W2t[k16][0];
#pragma unroll 8
        for (int j = 0; j < 128; j++) lg += hp[j] * wp[j];

        // softmax over 16 classes (within 16-lane group)
        float m = lg;
        for (int msk = 1; msk < NK; msk <<= 1) m = fmaxf(m, __shfl_xor(m, msk, NK));
        float ex = expf(lg - m);
        float s = ex;
        for (int msk = 1; msk < NK; msk <<= 1) s += __shfl_xor(s, msk, NK);
        sout[(size_t)(d0 + ni) * NK + k16] = ex / s;
    }
}

// ---------------- launcher ----------------
extern "C" void kernel_launch(void* const* d_in, const int* in_sizes, int n_in,
                              void* d_out, int out_size, void* d_ws, size_t ws_size,
                              hipStream_t stream){
    const float* x      = (const float*)d_in[0];
    const int*   ei     = (const int*)d_in[1];
    const int*   srcv   = ei;
    const int*   dstv   = ei + NEDGES;
    const float* W1     = (const float*)d_in[2];
    const float* att_s1 = (const float*)d_in[3];
    const float* att_d1 = (const float*)d_in[4];
    const float* b1     = (const float*)d_in[5];
    const float* W2     = (const float*)d_in[6];
    const float* att_s2 = (const float*)d_in[7];
    const float* att_d2 = (const float*)d_in[8];
    const float* b2     = (const float*)d_in[9];
    const float* Wm1    = (const float*)d_in[10];
    const float* bm1    = (const float*)d_in[11];
    const float* Wm2    = (const float*)d_in[12];
    const float* bm2    = (const float*)d_in[13];

    float* out     = (float*)d_out;                     // s: [N,16]
    float* emb_out = out + (size_t)NNODES * NK;         // embeddings: [N,64]

    float* ws  = (float*)d_ws;
    float* h1  = ws;                                    // N*256
    float* h2  = h1;                                    // N*64 (alias, lifetime disjoint)
    float* hL1 = h1 + (size_t)NNODES * HC1;             // N*256
    float* as1 = hL1 + (size_t)NNODES * HC1;            // N*8
    float* ad1 = as1 + (size_t)NNODES * NHEADS;         // N*8
    float* as2 = ad1 + (size_t)NNODES * NHEADS;         // N
    float* ad2 = as2 + NNODES;                          // N
    int* deg    = (int*)(ad2 + NNODES);                 // N
    int* rowptr = deg + NNODES;                         // N+1
    int* bsum   = rowptr + NNODES + 1;                  // 256
    int* boff   = bsum + 256;                           // 256
    int* fillc  = boff + 256;                           // N
    int* colv   = fillc + NNODES;                       // E

    hipMemsetAsync(deg, 0, NNODES * sizeof(int), stream);
    hipMemsetAsync(fillc, 0, NNODES * sizeof(int), stream);

    const int NB = (NNODES + 255) / 256;   // 196
    count_deg_k<<<(NEDGES + 255) / 256, 256, 0, stream>>>(dstv, deg);
    blocksum_k<<<NB, 256, 0, stream>>>(deg, bsum);
    scan_bsum_k<<<1, 256, 0, stream>>>(bsum, boff, NB);
    scan_write_k<<<NB, 256, 0, stream>>>(deg, boff, rowptr);
    fill_csr_k<<<(NEDGES + 255) / 256, 256, 0, stream>>>(srcv, dstv, rowptr, fillc, colv);

    // layer 1
    gemm_k<INC><<<dim3((NNODES + 63) / 64, HC1 / 64), 256, 0, stream>>>(x, W1, h1, NNODES, HC1);
    att1_k<<<NNODES / 4, 256, 0, stream>>>(h1, att_s1, att_d1, as1, ad1);
    gat1_agg_k<<<NNODES / 4, 256, 0, stream>>>(h1, as1, ad1, rowptr, colv, b1, hL1);

    // layer 2
    gemm_k<HC1><<<dim3((NNODES + 63) / 64, OUTC / 64), 256, 0, stream>>>(hL1, W2, h2, NNODES, OUTC);
    att2_k<<<NNODES / 4, 256, 0, stream>>>(h2, att_s2, att_d2, as2, ad2);
    gat2_agg_k<<<NNODES / 4, 256, 0, stream>>>(h2, as2, ad2, rowptr, colv, b2, emb_out);

    // MLP head + softmax
    mlp_k<<<512, 256, 0, stream>>>(emb_out, Wm1, bm1, Wm2, bm2, out);
}

// Round 3
// 413.039 us; speedup vs baseline: 1.1387x; 1.0030x over previous
//
#include <hip/hip_runtime.h>
#include <math.h>

#define NNODES 50000
#define NEDGES 400000
#define INC    128
#define HC1    256   // HEADS*HID
#define NHEADS 8
#define OUTC   64
#define NK     16
#define NEG_SLOPE 0.2f
#define EPS_F  1e-16f

typedef unsigned short u16;

__device__ __forceinline__ float lrelu(float x){ return x > 0.f ? x : NEG_SLOPE * x; }
__device__ __forceinline__ float eluf(float x){ return x > 0.f ? x : (expf(x) - 1.f); }
__device__ __forceinline__ float bf2f(u16 v){ return __uint_as_float((unsigned)v << 16); }
__device__ __forceinline__ u16 f2bf(float f){
    unsigned u = __float_as_uint(f);
    unsigned r = (u + 0x7FFFu + ((u >> 16) & 1u)) >> 16;   // RTNE
    return (u16)r;
}

// ---------------- CSR build ----------------
__global__ void count_deg_k(const int* __restrict__ dst, int* __restrict__ deg){
    int e = blockIdx.x * 256 + threadIdx.x;
    if (e < NEDGES) atomicAdd(&deg[dst[e]], 1);
}

__global__ void blocksum_k(const int* __restrict__ deg, int* __restrict__ bsum){
    __shared__ int sm[4];
    int i = blockIdx.x * 256 + threadIdx.x;
    int v = (i < NNODES) ? deg[i] : 0;
    for (int off = 1; off < 64; off <<= 1) v += __shfl_xor(v, off);
    int lane = threadIdx.x & 63, wid = threadIdx.x >> 6;
    if (lane == 0) sm[wid] = v;
    __syncthreads();
    if (threadIdx.x == 0) bsum[blockIdx.x] = sm[0] + sm[1] + sm[2] + sm[3];
}

__global__ void scan_bsum_k(const int* __restrict__ bsum, int* __restrict__ boff, int nb){
    int tid = threadIdx.x;
    int v = (tid < nb) ? bsum[tid] : 0;
    int orig = v;
    int lane = tid & 63, wid = tid >> 6;
    for (int off = 1; off < 64; off <<= 1){ int t = __shfl_up(v, off); if (lane >= off) v += t; }
    __shared__ int wsum[4];
    if (lane == 63) wsum[wid] = v;
    __syncthreads();
    int add = 0;
    for (int w = 0; w < wid; w++) add += wsum[w];
    v += add;
    if (tid < nb) boff[tid] = v - orig;
}

__global__ void scan_write_k(const int* __restrict__ deg, const int* __restrict__ boff,
                             int* __restrict__ rowptr){
    int tid = threadIdx.x;
    int i = blockIdx.x * 256 + tid;
    int v = (i < NNODES) ? deg[i] : 0;
    int lane = tid & 63, wid = tid >> 6;
    int sv = v;
    for (int off = 1; off < 64; off <<= 1){ int t = __shfl_up(sv, off); if (lane >= off) sv += t; }
    __shared__ int wsum[4];
    if (lane == 63) wsum[wid] = sv;
    __syncthreads();
    int add = 0;
    for (int w = 0; w < wid; w++) add += wsum[w];
    sv += add;
    if (i < NNODES) rowptr[i + 1] = boff[blockIdx.x] + sv;
    if (i == 0) rowptr[0] = 0;
}

__global__ void fill_csr_k(const int* __restrict__ src, const int* __restrict__ dst,
                           const int* __restrict__ rowptr, int* __restrict__ fillc,
                           int* __restrict__ col){
    int e = blockIdx.x * 256 + threadIdx.x;
    if (e < NEDGES){
        int d = dst[e];
        int pos = atomicAdd(&fillc[d], 1);
        col[rowptr[d] + pos] = src[e];
    }
}

// ---------------- fp32 tiled GEMM: C = A @ B, optional dual bf16 output ----------------
template<int KTOT, bool DUAL>
__global__ void gemm_k(const float* __restrict__ A, const float* __restrict__ B,
                       float* __restrict__ C, u16* __restrict__ Cb, int M, int Nc){
    __shared__ float As[16][68];
    __shared__ float Bs[16][68];
    int tx = threadIdx.x;
    int tm = tx >> 4, tn = tx & 15;
    int m0 = blockIdx.x * 64, n0 = blockIdx.y * 64;
    float acc[4][4];
#pragma unroll
    for (int i = 0; i < 4; i++)
#pragma unroll
        for (int j = 0; j < 4; j++) acc[i][j] = 0.f;

    int r  = tx >> 2;
    int kq = (tx & 3) * 4;
    int kk = tx >> 4;
    int nn = (tx & 15) * 4;

    for (int kt = 0; kt < KTOT; kt += 16){
        float4 av = make_float4(0.f, 0.f, 0.f, 0.f);
        int row = m0 + r;
        if (row < M) av = *(const float4*)(A + (size_t)row * KTOT + kt + kq);
        As[kq + 0][r] = av.x; As[kq + 1][r] = av.y; As[kq + 2][r] = av.z; As[kq + 3][r] = av.w;
        float4 bv = *(const float4*)(B + (size_t)(kt + kk) * Nc + n0 + nn);
        *(float4*)&Bs[kk][nn] = bv;
        __syncthreads();
#pragma unroll
        for (int k = 0; k < 16; k++){
            float4 a4 = *(float4*)&As[k][tm * 4];
            float4 b4 = *(float4*)&Bs[k][tn * 4];
            float a[4] = {a4.x, a4.y, a4.z, a4.w};
            float b[4] = {b4.x, b4.y, b4.z, b4.w};
#pragma unroll
            for (int i = 0; i < 4; i++)
#pragma unroll
                for (int j = 0; j < 4; j++) acc[i][j] += a[i] * b[j];
        }
        __syncthreads();
    }
#pragma unroll
    for (int i = 0; i < 4; i++){
        int row = m0 + tm * 4 + i;
        if (row < M){
            float4 o = make_float4(acc[i][0], acc[i][1], acc[i][2], acc[i][3]);
            *(float4*)(C + (size_t)row * Nc + n0 + tn * 4) = o;
            if (DUAL){
                ushort4 ob = make_ushort4(f2bf(o.x), f2bf(o.y), f2bf(o.z), f2bf(o.w));
                *(ushort4*)(Cb + (size_t)row * Nc + n0 + tn * 4) = ob;
            }
        }
    }
}

// ---------------- bf16-A GEMM: C = A_bf16 @ B_fp32, dual fp32+bf16 output ----------------
template<int KTOT>
__global__ void gemm_bf16A_k(const u16* __restrict__ A, const float* __restrict__ B,
                             float* __restrict__ C, u16* __restrict__ Cb, int M, int Nc){
    __shared__ float As[16][68];
    __shared__ float Bs[16][68];
    int tx = threadIdx.x;
    int tm = tx >> 4, tn = tx & 15;
    int m0 = blockIdx.x * 64, n0 = blockIdx.y * 64;
    float acc[4][4];
#pragma unroll
    for (int i = 0; i < 4; i++)
#pragma unroll
        for (int j = 0; j < 4; j++) acc[i][j] = 0.f;

    int r  = tx >> 2;
    int kq = (tx & 3) * 4;
    int kk = tx >> 4;
    int nn = (tx & 15) * 4;

    for (int kt = 0; kt < KTOT; kt += 16){
        float4 av = make_float4(0.f, 0.f, 0.f, 0.f);
        int row = m0 + r;
        if (row < M){
            ushort4 uv = *(const ushort4*)(A + (size_t)row * KTOT + kt + kq);
            av = make_float4(bf2f(uv.x), bf2f(uv.y), bf2f(uv.z), bf2f(uv.w));
        }
        As[kq + 0][r] = av.x; As[kq + 1][r] = av.y; As[kq + 2][r] = av.z; As[kq + 3][r] = av.w;
        float4 bv = *(const float4*)(B + (size_t)(kt + kk) * Nc + n0 + nn);
        *(float4*)&Bs[kk][nn] = bv;
        __syncthreads();
#pragma unroll
        for (int k = 0; k < 16; k++){
            float4 a4 = *(float4*)&As[k][tm * 4];
            float4 b4 = *(float4*)&Bs[k][tn * 4];
            float a[4] = {a4.x, a4.y, a4.z, a4.w};
            float b[4] = {b4.x, b4.y, b4.z, b4.w};
#pragma unroll
            for (int i = 0; i < 4; i++)
#pragma unroll
                for (int j = 0; j < 4; j++) acc[i][j] += a[i] * b[j];
        }
        __syncthreads();
    }
#pragma unroll
    for (int i = 0; i < 4; i++){
        int row = m0 + tm * 4 + i;
        if (row < M){
            float4 o = make_float4(acc[i][0], acc[i][1], acc[i][2], acc[i][3]);
            *(float4*)(C + (size_t)row * Nc + n0 + tn * 4) = o;
            ushort4 ob = make_ushort4(f2bf(o.x), f2bf(o.y), f2bf(o.z), f2bf(o.w));
            *(ushort4*)(Cb + (size_t)row * Nc + n0 + tn * 4) = ob;
        }
    }
}

// ---------------- attention scores ----------------
__global__ void att1_k(const float* __restrict__ h1, const float* __restrict__ att_s,
                       const float* __restrict__ att_d,
                       float* __restrict__ as1, float* __restrict__ ad1){
    int lane = threadIdx.x & 63, wid = threadIdx.x >> 6;
    int n = blockIdx.x * 4 + wid;
    float4 hv = *(const float4*)(h1 + (size_t)n * HC1 + lane * 4);
    float4 sv = *(const float4*)(att_s + lane * 4);
    float4 dv = *(const float4*)(att_d + lane * 4);
    float ps = hv.x * sv.x + hv.y * sv.y + hv.z * sv.z + hv.w * sv.w;
    float pd = hv.x * dv.x + hv.y * dv.y + hv.z * dv.z + hv.w * dv.w;
    for (int m = 1; m < 8; m <<= 1){ ps += __shfl_xor(ps, m); pd += __shfl_xor(pd, m); }
    if ((lane & 7) == 0){
        int h = lane >> 3;
        as1[n * NHEADS + h] = ps;
        ad1[n * NHEADS + h] = pd;
    }
}

__global__ void att2_k(const float* __restrict__ h2, const float* __restrict__ att_s,
                       const float* __restrict__ att_d,
                       float* __restrict__ as2, float* __restrict__ ad2){
    int lane = threadIdx.x & 63, wid = threadIdx.x >> 6;
    int n = blockIdx.x * 4 + wid;
    float hv = h2[(size_t)n * OUTC + lane];
    float ps = hv * att_s[lane];
    float pd = hv * att_d[lane];
    for (int m = 1; m < 64; m <<= 1){ ps += __shfl_xor(ps, m); pd += __shfl_xor(pd, m); }
    if (lane == 0){ as2[n] = ps; ad2[n] = pd; }
}

// ---------------- GAT layer 1 aggregation: bf16 gather, bf16 output ----------------
__global__ void gat1_agg_k(const u16* __restrict__ h1b, const float* __restrict__ as1,
                           const float* __restrict__ ad1, const int* __restrict__ rowptr,
                           const int* __restrict__ col, const float* __restrict__ b1,
                           u16* __restrict__ outb){
    int lane = threadIdx.x & 63, wid = threadIdx.x >> 6;
    int d = blockIdx.x * 4 + wid;
    int row0 = rowptr[d];
    int deg  = rowptr[d + 1] - row0;

    int h8 = lane & 7, j = lane >> 3;
    float adst      = ad1[d * NHEADS + h8];
    float asrc_self = as1[d * NHEADS + h8];
    float e_self = lrelu(asrc_self + adst);

    float vmax = e_self;
    for (int base = 0; base < deg; base += 8){
        int idx = base + j;
        if (idx < deg){
            int s = col[row0 + idx];
            vmax = fmaxf(vmax, lrelu(as1[s * NHEADS + h8] + adst));
        }
    }
    vmax = fmaxf(vmax, __shfl_xor(vmax, 8));
    vmax = fmaxf(vmax, __shfl_xor(vmax, 16));
    vmax = fmaxf(vmax, __shfl_xor(vmax, 32));

    float vsum = (j == 0) ? expf(e_self - vmax) : 0.f;
    for (int base = 0; base < deg; base += 8){
        int idx = base + j;
        if (idx < deg){
            int s = col[row0 + idx];
            vsum += expf(lrelu(as1[s * NHEADS + h8] + adst) - vmax);
        }
    }
    vsum += __shfl_xor(vsum, 8);
    vsum += __shfl_xor(vsum, 16);
    vsum += __shfl_xor(vsum, 32);
    float den = vsum + EPS_F;

    int hc = lane >> 3;
    float m_c    = __shfl(vmax, hc);
    float rden_c = 1.f / __shfl(den, hc);
    float adst_c = __shfl(adst, hc);
    float asrc_d = __shfl(asrc_self, hc);
    int cbase = lane * 4;

    float alpha = expf(lrelu(asrc_d + adst_c) - m_c) * rden_c;  // self-loop
    ushort4 us = *(const ushort4*)(h1b + (size_t)d * HC1 + cbase);
    float4 acc = make_float4(alpha * bf2f(us.x), alpha * bf2f(us.y),
                             alpha * bf2f(us.z), alpha * bf2f(us.w));

    for (int idx = 0; idx < deg; idx++){
        int s = col[row0 + idx];
        float a = expf(lrelu(as1[s * NHEADS + hc] + adst_c) - m_c) * rden_c;
        ushort4 u4 = *(const ushort4*)(h1b + (size_t)s * HC1 + cbase);
        acc.x += a * bf2f(u4.x); acc.y += a * bf2f(u4.y);
        acc.z += a * bf2f(u4.z); acc.w += a * bf2f(u4.w);
    }
    float4 bb = *(const float4*)(b1 + cbase);
    ushort4 ob = make_ushort4(f2bf(eluf(acc.x + bb.x)), f2bf(eluf(acc.y + bb.y)),
                              f2bf(eluf(acc.z + bb.z)), f2bf(eluf(acc.w + bb.w)));
    *(ushort4*)(outb + (size_t)d * HC1 + cbase) = ob;
}

// ---------------- GAT layer 2 aggregation: bf16 gather, fp32 output ----------------
__global__ void gat2_agg_k(const u16* __restrict__ h2b, const float* __restrict__ as2,
                           const float* __restrict__ ad2, const int* __restrict__ rowptr,
                           const int* __restrict__ col, const float* __restrict__ b2,
                           float* __restrict__ emb){
    int lane = threadIdx.x & 63, wid = threadIdx.x >> 6;
    int d = blockIdx.x * 4 + wid;
    int row0 = rowptr[d];
    int deg  = rowptr[d + 1] - row0;

    float adst = ad2[d];
    float e_self = lrelu(as2[d] + adst);
    float vmax = e_self;
    for (int base = 0; base < deg; base += 64){
        int idx = base + lane;
        if (idx < deg){
            int s = col[row0 + idx];
            vmax = fmaxf(vmax, lrelu(as2[s] + adst));
        }
    }
    for (int m = 1; m < 64; m <<= 1) vmax = fmaxf(vmax, __shfl_xor(vmax, m));

    float vsum = (lane == 0) ? expf(e_self - vmax) : 0.f;
    for (int base = 0; base < deg; base += 64){
        int idx = base + lane;
        if (idx < deg){
            int s = col[row0 + idx];
            vsum += expf(lrelu(as2[s] + adst) - vmax);
        }
    }
    for (int m = 1; m < 64; m <<= 1) vsum += __shfl_xor(vsum, m);
    float rden = 1.f / (vsum + EPS_F);

    float alpha = expf(e_self - vmax) * rden;
    float acc = alpha * bf2f(h2b[(size_t)d * OUTC + lane]);
    for (int idx = 0; idx < deg; idx++){
        int s = col[row0 + idx];
        float a = expf(lrelu(as2[s] + adst) - vmax) * rden;
        acc += a * bf2f(h2b[(size_t)s * OUTC + lane]);
    }
    emb[(size_t)d * OUTC + lane] = acc + b2[lane];
}

// ---------------- MLP head + softmax: LDS-resident weights, 4 nodes/wave ----------------
__global__ __launch_bounds__(256, 2) void mlp_k(const float* __restrict__ emb,
                      const float* __restrict__ Wm1, const float* __restrict__ bm1,
                      const float* __restrict__ Wm2, const float* __restrict__ bm2,
                      float* __restrict__ sout){
    __shared__ float W1a[64][64];
    __shared__ float W1b[64][64];
    __shared__ float W2t[16][132];
    __shared__ float b1s[128];
    __shared__ float b2s[16];
    __shared__ float semb[4][64][4];
    __shared__ float shid[4][4][132];

    int tx = threadIdx.x;
    for (int i = tx; i < 64 * 64; i += 256){
        int c = i >> 6, l = i & 63;
        W1a[c][l] = Wm1[c * 128 + l];
        W1b[c][l] = Wm1[c * 128 + 64 + l];
    }
    for (int i = tx; i < 16 * 128; i += 256){
        int k = i >> 7, j = i & 127;
        W2t[k][j] = Wm2[j * NK + k];
    }
    if (tx < 128) b1s[tx] = bm1[tx];
    if (tx < 16)  b2s[tx] = bm2[tx];
    __syncthreads();

    int lane = tx & 63, wid = tx >> 6;
    int k16 = lane & 15, ni = lane >> 4;

    for (int base = blockIdx.x * 16; base < NNODES; base += gridDim.x * 16){
        int d0 = base + wid * 4;
#pragma unroll
        for (int i = 0; i < 4; i++)
            semb[wid][lane][i] = emb[(size_t)(d0 + i) * OUTC + lane];
        __syncthreads();

        float2 acc[4];
#pragma unroll
        for (int i = 0; i < 4; i++) acc[i] = make_float2(b1s[lane], b1s[64 + lane]);
#pragma unroll 8
        for (int c = 0; c < 64; c++){
            float wa = W1a[c][lane];
            float wb = W1b[c][lane];
            float4 e = *(const float4*)&semb[wid][c][0];
            acc[0].x += e.x * wa; acc[0].y += e.x * wb;
            acc[1].x += e.y * wa; acc[1].y += e.y * wb;
            acc[2].x += e.z * wa; acc[2].y += e.z * wb;
            acc[3].x += e.w * wa; acc[3].y += e.w * wb;
        }
#pragma unroll
        for (int i = 0; i < 4; i++){
            shid[wid][i][lane]      = fmaxf(acc[i].x, 0.f);
            shid[wid][i][64 + lane] = fmaxf(acc[i].y, 0.f);
        }
        __syncthreads();

        float lg = b2s[k16];
        const float* hp = &shid[wid][ni][0];
        const float* wp = &W2t[k16][0];
#pragma unroll 8
        for (int j = 0; j < 128; j++) lg += hp[j] * wp[j];

        float m = lg;
        for (int msk = 1; msk < NK; msk <<= 1) m = fmaxf(m, __shfl_xor(m, msk, NK));
        float ex = expf(lg - m);
        float s = ex;
        for (int msk = 1; msk < NK; msk <<= 1) s += __shfl_xor(s, msk, NK);
        sout[(size_t)(d0 + ni) * NK + k16] = ex / s;
    }
}

// ---------------- launcher ----------------
extern "C" void kernel_launch(void* const* d_in, const int* in_sizes, int n_in,
                              void* d_out, int out_size, void* d_ws, size_t ws_size,
                              hipStream_t stream){
    const float* x      = (const float*)d_in[0];
    const int*   ei     = (const int*)d_in[1];
    const int*   srcv   = ei;
    const int*   dstv   = ei + NEDGES;
    const float* W1     = (const float*)d_in[2];
    const float* att_s1 = (const float*)d_in[3];
    const float* att_d1 = (const float*)d_in[4];
    const float* b1     = (const float*)d_in[5];
    const float* W2     = (const float*)d_in[6];
    const float* att_s2 = (const float*)d_in[7];
    const float* att_d2 = (const float*)d_in[8];
    const float* b2     = (const float*)d_in[9];
    const float* Wm1    = (const float*)d_in[10];
    const float* bm1    = (const float*)d_in[11];
    const float* Wm2    = (const float*)d_in[12];
    const float* bm2    = (const float*)d_in[13];

    float* out     = (float*)d_out;                     // s: [N,16]
    float* emb_out = out + (size_t)NNODES * NK;         // embeddings: [N,64]

    // workspace layout
    float* ws   = (float*)d_ws;
    float* h1   = ws;                                   // N*256 fp32 (region0; reused for h2/h2b later)
    u16*   h1b  = (u16*)(h1 + (size_t)NNODES * HC1);    // N*256 bf16 = N*128 floats
    u16*   hL1b = (u16*)((float*)h1b + (size_t)NNODES * 128);  // N*256 bf16
    float* as1  = (float*)hL1b + (size_t)NNODES * 128;  // N*8
    float* ad1  = as1 + (size_t)NNODES * NHEADS;        // N*8
    float* as2  = ad1 + (size_t)NNODES * NHEADS;        // N
    float* ad2  = as2 + NNODES;                         // N
    int* deg    = (int*)(ad2 + NNODES);                 // N
    int* rowptr = deg + NNODES;                         // N+1
    int* bsum   = rowptr + NNODES + 1;                  // 256
    int* boff   = bsum + 256;                           // 256
    int* fillc  = boff + 256;                           // N
    int* colv   = fillc + NNODES;                       // E
    // region0 reuse (h1 fp32 dead after att1+gat1): h2 fp32 + h2b bf16
    float* h2  = h1;                                    // N*64 fp32
    u16*   h2b = (u16*)(h2 + (size_t)NNODES * OUTC);    // N*64 bf16

    hipMemsetAsync(deg, 0, NNODES * sizeof(int), stream);
    hipMemsetAsync(fillc, 0, NNODES * sizeof(int), stream);

    const int NB = (NNODES + 255) / 256;
    count_deg_k<<<(NEDGES + 255) / 256, 256, 0, stream>>>(dstv, deg);
    blocksum_k<<<NB, 256, 0, stream>>>(deg, bsum);
    scan_bsum_k<<<1, 256, 0, stream>>>(bsum, boff, NB);
    scan_write_k<<<NB, 256, 0, stream>>>(deg, boff, rowptr);
    fill_csr_k<<<(NEDGES + 255) / 256, 256, 0, stream>>>(srcv, dstv, rowptr, fillc, colv);

    // layer 1: h1 = x@W1 (fp32 + bf16 copy)
    gemm_k<INC, true><<<dim3((NNODES + 63) / 64, HC1 / 64), 256, 0, stream>>>(x, W1, h1, h1b, NNODES, HC1);
    att1_k<<<NNODES / 4, 256, 0, stream>>>(h1, att_s1, att_d1, as1, ad1);
    gat1_agg_k<<<NNODES / 4, 256, 0, stream>>>(h1b, as1, ad1, rowptr, colv, b1, hL1b);

    // layer 2: h2 = hL1b@W2 (bf16 A, fp32 + bf16 out)
    gemm_bf16A_k<HC1><<<dim3((NNODES + 63) / 64, OUTC / 64), 256, 0, stream>>>(hL1b, W2, h2, h2b, NNODES, OUTC);
    att2_k<<<NNODES / 4, 256, 0, stream>>>(h2, att_s2, att_d2, as2, ad2);
    gat2_agg_k<<<NNODES / 4, 256, 0, stream>>>(h2b, as2, ad2, rowptr, colv, b2, emb_out);

    // MLP head + softmax
    mlp_k<<<512, 256, 0, stream>>>(emb_out, Wm1, bm1, Wm2, bm2, out);
}